// Round 1
// baseline (607.843 us; speedup 1.0000x reference)
//
#include <hip/hip_runtime.h>

// Problem constants (from reference setup_inputs)
#define NATOMS 32768
#define NFEAT 1920
#define HIDDEN 256
#define NSPEC 4
#define NSTRUCT 512
#define BM 64
#define MTILES 516               // max padded tiles: <=515 real, +1 slack
#define MPAD (MTILES * BM)       // 33024

typedef __bf16 bf16x8 __attribute__((ext_vector_type(8)));
typedef float f32x4 __attribute__((ext_vector_type(4)));
typedef float f4v __attribute__((ext_vector_type(4)));
typedef unsigned short us4 __attribute__((ext_vector_type(4)));

// Workspace layout (bytes). Total ~37.2 MB.
#define WS_INTS 0                                        // [0..3] counts, [4..7] cursors, [8..12] off
#define WS_PERM 256
#define WS_W1T (WS_PERM + MPAD * 4)                      // 132352
#define WS_W2T (WS_W1T + NSPEC * HIDDEN * NFEAT * 2)     // 4064512
#define WS_W3T (WS_W2T + NSPEC * HIDDEN * HIDDEN * 2)    // 4588800
#define WS_W4T (WS_W3T + NSPEC * HIDDEN * HIDDEN * 2)    // 5113088
#define WS_H1  (WS_W4T + 4096)                           // 5117184
#define WS_H2  (WS_H1 + (size_t)MPAD * HIDDEN * 2)       // 22025472

__device__ __forceinline__ unsigned short f2bf(float f) {
  unsigned int u = __float_as_uint(f);
  u += 0x7fffu + ((u >> 16) & 1u);           // round-to-nearest-even
  return (unsigned short)(u >> 16);
}
__device__ __forceinline__ float bf2f(unsigned short s) {
  return __uint_as_float(((unsigned int)s) << 16);
}
__device__ __forceinline__ float silu_n(float x) {
  return (x / (1.f + __expf(-x))) * 1.6765f; // variance-preserving SiLU
}

// ---- prep kernels -------------------------------------------------------

__global__ void k_init(int* ints, int* perm, float* out) {
  int i = blockIdx.x * blockDim.x + threadIdx.x;
  if (i < MPAD) perm[i] = -1;
  if (i < NSTRUCT) out[i] = 0.f;
  if (i < 8) ints[i] = 0;
}

__global__ void k_count(const int* __restrict__ species, int* counts) {
  int i = blockIdx.x * blockDim.x + threadIdx.x;
  if (i < NATOMS) atomicAdd(&counts[species[i]], 1);
}

__global__ void k_offsets(int* ints) {
  int* counts = ints;
  int* cursors = ints + 4;
  int* off = ints + 8;
  off[0] = 0;
  for (int s = 0; s < NSPEC; ++s) {
    off[s + 1] = off[s] + ((counts[s] + 63) & ~63);
    cursors[s] = off[s];
  }
}

__global__ void k_scatter(const int* __restrict__ species, int* ints, int* perm) {
  int i = blockIdx.x * blockDim.x + threadIdx.x;
  if (i < NATOMS) {
    int s = species[i];
    int pos = atomicAdd(&ints[4 + s], 1);
    perm[pos] = i;
  }
}

// f32 [S][K][N] -> bf16 [S][N][K]  (64x64 LDS tiled transpose)
__global__ void k_transpose(const float* __restrict__ src, unsigned short* __restrict__ dst,
                            int K, int N) {
  __shared__ unsigned short T[64][72];
  int ntN = N >> 6, ntK = K >> 6;
  int per = ntK * ntN;
  int b = blockIdx.x;
  int s = b / per, rem = b % per;
  int k0 = (rem / ntN) << 6;
  int n0 = (rem % ntN) << 6;
  int tid = threadIdx.x;
  int r = tid >> 2, cb = (tid & 3) << 4;
  const float* p = src + ((size_t)s * K + k0 + r) * N + n0 + cb;
#pragma unroll
  for (int j = 0; j < 16; j += 4) {
    f4v v = *(const f4v*)(p + j);
#pragma unroll
    for (int e = 0; e < 4; ++e) T[r][cb + j + e] = f2bf(v[e]);
  }
  __syncthreads();
  unsigned short* drow = dst + ((size_t)s * N + n0 + r) * K + k0 + cb;
#pragma unroll
  for (int j = 0; j < 4; ++j) {
    us4 o;
#pragma unroll
    for (int e = 0; e < 4; ++e) o[e] = T[cb + j * 4 + e][r];
    *(us4*)(drow + j * 4) = o;
  }
}

__global__ void k_w4(const float* __restrict__ src, unsigned short* __restrict__ dst) {
  int i = blockIdx.x * 256 + threadIdx.x;   // 4*256 elems
  dst[i] = f2bf(src[i]);
}

// ---- grouped MFMA GEMM layer -------------------------------------------
// X[Mpad x K] (f32-gathered or bf16) @ Wt[sp][N=256][K] -> H[Mpad x 256], silu_n epilogue.
// Block: 256 thr = 4 waves; tile BM=64 x BN=256; wave w owns cols [64w, 64w+64).
template <int K, bool GATHER>
__global__ __launch_bounds__(256) void k_mlp(
    const float* __restrict__ xf, const unsigned short* __restrict__ xb,
    const unsigned short* __restrict__ Wt, unsigned short* __restrict__ Hout,
    const int* __restrict__ perm, const int* __restrict__ off, float scale) {
  __shared__ unsigned short Alds[BM][72];
  __shared__ unsigned short Blds[HIDDEN][72];

  int rowbase = blockIdx.x * BM;
  int tid = threadIdx.x;
  int w = tid >> 6, l = tid & 63;

  int sp;
  if (rowbase < off[1]) sp = 0;
  else if (rowbase < off[2]) sp = 1;
  else if (rowbase < off[3]) sp = 2;
  else sp = 3;

  int ar = tid >> 2;            // staged A-row (0..63)
  int ac = (tid & 3) << 4;      // staged A-col base (0,16,32,48)
  long asrc = 0;
  if constexpr (GATHER) asrc = perm[rowbase + ar];

  const unsigned short* wrow = Wt + ((size_t)sp * HIDDEN + tid) * K;

  f32x4 zero4 = {0.f, 0.f, 0.f, 0.f};
  f32x4 acc[4][4];
#pragma unroll
  for (int m = 0; m < 4; ++m)
#pragma unroll
    for (int n = 0; n < 4; ++n) acc[m][n] = zero4;

  for (int k0 = 0; k0 < K; k0 += 64) {
    // stage A (64 rows x 64 k, bf16)
    if constexpr (GATHER) {
      if (asrc >= 0) {
        const float* p = xf + asrc * (long)K + k0 + ac;
#pragma unroll
        for (int j = 0; j < 16; j += 4) {
          f4v v = *(const f4v*)(p + j);
          us4 u;
#pragma unroll
          for (int e = 0; e < 4; ++e) u[e] = f2bf(v[e]);
          *(us4*)&Alds[ar][ac + j] = u;
        }
      } else {
        us4 z = {0, 0, 0, 0};
#pragma unroll
        for (int j = 0; j < 16; j += 4) *(us4*)&Alds[ar][ac + j] = z;
      }
    } else {
      const unsigned short* p = xb + (size_t)(rowbase + ar) * K + k0 + ac;
      *(uint4*)&Alds[ar][ac] = *(const uint4*)p;
      *(uint4*)&Alds[ar][ac + 8] = *(const uint4*)(p + 8);
    }
    // stage B (thread t = output col n, 64 k of bf16 = 128 B)
    {
      const uint4* s4 = (const uint4*)(wrow + k0);
#pragma unroll
      for (int j = 0; j < 8; ++j) *(uint4*)&Blds[tid][j * 8] = s4[j];
    }
    __syncthreads();

    int lr = l & 15, lg = l >> 4;
#pragma unroll
    for (int kk = 0; kk < 2; ++kk) {
      bf16x8 a[4], b[4];
#pragma unroll
      for (int m = 0; m < 4; ++m)
        a[m] = *(const bf16x8*)&Alds[m * 16 + lr][kk * 32 + lg * 8];
#pragma unroll
      for (int n = 0; n < 4; ++n)
        b[n] = *(const bf16x8*)&Blds[w * 64 + n * 16 + lr][kk * 32 + lg * 8];
#pragma unroll
      for (int m = 0; m < 4; ++m)
#pragma unroll
        for (int n = 0; n < 4; ++n)
          acc[m][n] = __builtin_amdgcn_mfma_f32_16x16x32_bf16(a[m], b[n], acc[m][n], 0, 0, 0);
    }
    __syncthreads();
  }

  // epilogue: D[row=m*16+lg*4+r][col=w*64+n*16+lr]
  int lr = l & 15, lg = l >> 4;
#pragma unroll
  for (int m = 0; m < 4; ++m)
#pragma unroll
    for (int n = 0; n < 4; ++n)
#pragma unroll
      for (int r = 0; r < 4; ++r) {
        float v = acc[m][n][r] * scale;
        Hout[(size_t)(rowbase + m * 16 + lg * 4 + r) * HIDDEN + w * 64 + n * 16 + lr] =
            f2bf(silu_n(v));
      }
}

// ---- layer 4 + segment reduction ---------------------------------------
__global__ void k_l4(const unsigned short* __restrict__ H3, const unsigned short* __restrict__ W4t,
                     const int* __restrict__ perm, const int* __restrict__ species,
                     const int* __restrict__ sidx, const float* __restrict__ coeff,
                     float* __restrict__ out) {
  int w = threadIdx.x >> 6, l = threadIdx.x & 63;
  int row = blockIdx.x * 4 + w;
  int src = perm[row];
  if (src < 0) return;
  int sp = species[src];
  us4 h = *(const us4*)&H3[(size_t)row * HIDDEN + l * 4];
  us4 wv = *(const us4*)&W4t[sp * HIDDEN + l * 4];
  float sum = 0.f;
#pragma unroll
  for (int e = 0; e < 4; ++e) sum += bf2f(h[e]) * bf2f(wv[e]);
#pragma unroll
  for (int d = 32; d >= 1; d >>= 1) sum += __shfl_xor(sum, d, 64);
  if (l == 0)
    atomicAdd(&out[sidx[src]], sum * (0.0625f * 0.125f) + coeff[sp]);
}

// ---- launcher -----------------------------------------------------------
extern "C" void kernel_launch(void* const* d_in, const int* in_sizes, int n_in,
                              void* d_out, int out_size, void* d_ws, size_t ws_size,
                              hipStream_t stream) {
  const float* features = (const float*)d_in[0];
  const float* W1 = (const float*)d_in[1];
  const float* W2 = (const float*)d_in[2];
  const float* W3 = (const float*)d_in[3];
  const float* W4 = (const float*)d_in[4];
  const float* coeff = (const float*)d_in[5];
  const int* species = (const int*)d_in[6];
  const int* sidx = (const int*)d_in[7];
  float* out = (float*)d_out;

  char* ws = (char*)d_ws;
  int* ints = (int*)(ws + WS_INTS);
  int* perm = (int*)(ws + WS_PERM);
  unsigned short* W1t = (unsigned short*)(ws + WS_W1T);
  unsigned short* W2t = (unsigned short*)(ws + WS_W2T);
  unsigned short* W3t = (unsigned short*)(ws + WS_W3T);
  unsigned short* W4t = (unsigned short*)(ws + WS_W4T);
  unsigned short* H1 = (unsigned short*)(ws + WS_H1);
  unsigned short* H2 = (unsigned short*)(ws + WS_H2);

  // species bucketing
  k_init<<<(MPAD + 255) / 256, 256, 0, stream>>>(ints, perm, out);
  k_count<<<NATOMS / 256, 256, 0, stream>>>(species, ints);
  k_offsets<<<1, 1, 0, stream>>>(ints);
  k_scatter<<<NATOMS / 256, 256, 0, stream>>>(species, ints, perm);

  // weight prep: bf16, [sp][N][K] transposed
  k_transpose<<<NSPEC * (NFEAT / 64) * (HIDDEN / 64), 256, 0, stream>>>(W1, W1t, NFEAT, HIDDEN);
  k_transpose<<<NSPEC * (HIDDEN / 64) * (HIDDEN / 64), 256, 0, stream>>>(W2, W2t, HIDDEN, HIDDEN);
  k_transpose<<<NSPEC * (HIDDEN / 64) * (HIDDEN / 64), 256, 0, stream>>>(W3, W3t, HIDDEN, HIDDEN);
  k_w4<<<NSPEC, 256, 0, stream>>>(W4, W4t);

  // MLP layers
  const float s1 = 1.f / sqrtf((float)NFEAT);
  const float s2 = 1.f / 16.f;
  k_mlp<NFEAT, true><<<MTILES, 256, 0, stream>>>(features, nullptr, W1t, H1, perm, ints + 8, s1);
  k_mlp<HIDDEN, false><<<MTILES, 256, 0, stream>>>(nullptr, H1, W2t, H2, perm, ints + 8, s2);
  k_mlp<HIDDEN, false><<<MTILES, 256, 0, stream>>>(nullptr, H2, W3t, H1, perm, ints + 8, s2);

  // layer 4 + segment sum + composition term
  k_l4<<<MPAD / 4, 256, 0, stream>>>(H1, W4t, perm, species, sidx, coeff, out);
}

// Round 2
// 254.262 us; speedup vs baseline: 2.3906x; 2.3906x over previous
//
#include <hip/hip_runtime.h>

// Problem constants (from reference setup_inputs)
#define NATOMS 32768
#define NFEAT 1920
#define HIDDEN 256
#define NSPEC 4
#define NSTRUCT 512
#define BM 64
#define MTILES 516               // max padded tiles: <=515 real, +1 slack
#define MPAD (MTILES * BM)       // 33024

typedef __bf16 bf16x8 __attribute__((ext_vector_type(8)));
typedef float f32x4 __attribute__((ext_vector_type(4)));
typedef float f4v __attribute__((ext_vector_type(4)));
typedef unsigned short us4 __attribute__((ext_vector_type(4)));

// Workspace layout (bytes). Total ~37.2 MB.
#define WS_INTS 0                                        // [0..3] counts, [4..7] cursors, [8..12] off
#define WS_PERM 256
#define WS_W1T (WS_PERM + MPAD * 4)                      // 132352
#define WS_W2T (WS_W1T + NSPEC * HIDDEN * NFEAT * 2)     // 4064512
#define WS_W3T (WS_W2T + NSPEC * HIDDEN * HIDDEN * 2)    // 4588800
#define WS_W4T (WS_W3T + NSPEC * HIDDEN * HIDDEN * 2)    // 5113088
#define WS_H1  (WS_W4T + 4096)                           // 5117184
#define WS_H2  (WS_H1 + (size_t)MPAD * HIDDEN * 2)       // 22025472

__device__ __forceinline__ unsigned short f2bf(float f) {
  unsigned int u = __float_as_uint(f);
  u += 0x7fffu + ((u >> 16) & 1u);           // round-to-nearest-even
  return (unsigned short)(u >> 16);
}
__device__ __forceinline__ float bf2f(unsigned short s) {
  return __uint_as_float(((unsigned int)s) << 16);
}
__device__ __forceinline__ float silu_n(float x) {
  return (x / (1.f + __expf(-x))) * 1.6765f; // variance-preserving SiLU
}

// ---- prep kernels -------------------------------------------------------

__global__ void k_init(int* ints, int* perm, float* out) {
  int i = blockIdx.x * blockDim.x + threadIdx.x;
  if (i < MPAD) perm[i] = -1;
  if (i < NSTRUCT) out[i] = 0.f;
  if (i < 8) ints[i] = 0;
}

// Block-aggregated species count: ballots -> LDS -> 4 atomics per block.
__global__ void k_count(const int* __restrict__ species, int* counts) {
  __shared__ int c[NSPEC];
  int tid = threadIdx.x;
  if (tid < NSPEC) c[tid] = 0;
  __syncthreads();
  int s = species[blockIdx.x * 256 + tid];
  int lane = tid & 63;
#pragma unroll
  for (int sp = 0; sp < NSPEC; ++sp) {
    unsigned long long m = __ballot(s == sp);
    if (lane == 0 && m) atomicAdd(&c[sp], __popcll(m));
  }
  __syncthreads();
  if (tid < NSPEC && c[tid]) atomicAdd(&counts[tid], c[tid]);
}

__global__ void k_offsets(int* ints) {
  int* counts = ints;
  int* cursors = ints + 4;
  int* off = ints + 8;
  off[0] = 0;
  for (int s = 0; s < NSPEC; ++s) {
    off[s + 1] = off[s] + ((counts[s] + 63) & ~63);
    cursors[s] = off[s];
  }
}

// Block-aggregated scatter: one range-reserving atomic per (block, species);
// thread position = block base + wave prefix + intra-wave ballot rank.
__global__ void k_scatter(const int* __restrict__ species, int* ints, int* perm) {
  __shared__ int cnt[4][NSPEC];   // [wave][species]
  __shared__ int base[NSPEC];
  int tid = threadIdx.x;
  int w = tid >> 6, lane = tid & 63;
  int i = blockIdx.x * 256 + tid;
  int s = species[i];
  unsigned long long m0 = __ballot(s == 0);
  unsigned long long m1 = __ballot(s == 1);
  unsigned long long m2 = __ballot(s == 2);
  unsigned long long m3 = __ballot(s == 3);
  if (lane == 0) {
    cnt[w][0] = __popcll(m0);
    cnt[w][1] = __popcll(m1);
    cnt[w][2] = __popcll(m2);
    cnt[w][3] = __popcll(m3);
  }
  __syncthreads();
  if (tid < NSPEC) {
    int t = cnt[0][tid] + cnt[1][tid] + cnt[2][tid] + cnt[3][tid];
    base[tid] = t ? atomicAdd(&ints[4 + tid], t) : 0;
  }
  __syncthreads();
  unsigned long long mm = (s == 0) ? m0 : (s == 1) ? m1 : (s == 2) ? m2 : m3;
  int pos = base[s] + __popcll(mm & ((1ull << lane) - 1ull));
#pragma unroll
  for (int ww = 0; ww < 4; ++ww)
    if (ww < w) pos += cnt[ww][s];
  perm[pos] = i;
}

// f32 [S][K][N] -> bf16 [S][N][K]  (64x64 LDS tiled transpose)
__global__ void k_transpose(const float* __restrict__ src, unsigned short* __restrict__ dst,
                            int K, int N) {
  __shared__ unsigned short T[64][72];
  int ntN = N >> 6, ntK = K >> 6;
  int per = ntK * ntN;
  int b = blockIdx.x;
  int s = b / per, rem = b % per;
  int k0 = (rem / ntN) << 6;
  int n0 = (rem % ntN) << 6;
  int tid = threadIdx.x;
  int r = tid >> 2, cb = (tid & 3) << 4;
  const float* p = src + ((size_t)s * K + k0 + r) * N + n0 + cb;
#pragma unroll
  for (int j = 0; j < 16; j += 4) {
    f4v v = *(const f4v*)(p + j);
#pragma unroll
    for (int e = 0; e < 4; ++e) T[r][cb + j + e] = f2bf(v[e]);
  }
  __syncthreads();
  unsigned short* drow = dst + ((size_t)s * N + n0 + r) * K + k0 + cb;
#pragma unroll
  for (int j = 0; j < 4; ++j) {
    us4 o;
#pragma unroll
    for (int e = 0; e < 4; ++e) o[e] = T[cb + j * 4 + e][r];
    *(us4*)(drow + j * 4) = o;
  }
}

__global__ void k_w4(const float* __restrict__ src, unsigned short* __restrict__ dst) {
  int i = blockIdx.x * 256 + threadIdx.x;   // 4*256 elems
  dst[i] = f2bf(src[i]);
}

// ---- grouped MFMA GEMM layer -------------------------------------------
// X[Mpad x K] (f32-gathered or bf16) @ Wt[sp][N=256][K] -> H[Mpad x 256], silu_n epilogue.
// Block: 256 thr = 4 waves; tile BM=64 x BN=256; wave w owns cols [64w, 64w+64).
template <int K, bool GATHER>
__global__ __launch_bounds__(256) void k_mlp(
    const float* __restrict__ xf, const unsigned short* __restrict__ xb,
    const unsigned short* __restrict__ Wt, unsigned short* __restrict__ Hout,
    const int* __restrict__ perm, const int* __restrict__ off, float scale) {
  __shared__ unsigned short Alds[BM][72];
  __shared__ unsigned short Blds[HIDDEN][72];

  int rowbase = blockIdx.x * BM;
  int tid = threadIdx.x;
  int w = tid >> 6, l = tid & 63;

  int sp;
  if (rowbase < off[1]) sp = 0;
  else if (rowbase < off[2]) sp = 1;
  else if (rowbase < off[3]) sp = 2;
  else sp = 3;

  int ar = tid >> 2;            // staged A-row (0..63)
  int ac = (tid & 3) << 4;      // staged A-col base (0,16,32,48)
  long asrc = 0;
  if constexpr (GATHER) asrc = perm[rowbase + ar];

  const unsigned short* wrow = Wt + ((size_t)sp * HIDDEN + tid) * K;

  f32x4 zero4 = {0.f, 0.f, 0.f, 0.f};
  f32x4 acc[4][4];
#pragma unroll
  for (int m = 0; m < 4; ++m)
#pragma unroll
    for (int n = 0; n < 4; ++n) acc[m][n] = zero4;

  for (int k0 = 0; k0 < K; k0 += 64) {
    // stage A (64 rows x 64 k, bf16)
    if constexpr (GATHER) {
      if (asrc >= 0) {
        const float* p = xf + asrc * (long)K + k0 + ac;
#pragma unroll
        for (int j = 0; j < 16; j += 4) {
          f4v v = *(const f4v*)(p + j);
          us4 u;
#pragma unroll
          for (int e = 0; e < 4; ++e) u[e] = f2bf(v[e]);
          *(us4*)&Alds[ar][ac + j] = u;
        }
      } else {
        us4 z = {0, 0, 0, 0};
#pragma unroll
        for (int j = 0; j < 16; j += 4) *(us4*)&Alds[ar][ac + j] = z;
      }
    } else {
      const unsigned short* p = xb + (size_t)(rowbase + ar) * K + k0 + ac;
      *(uint4*)&Alds[ar][ac] = *(const uint4*)p;
      *(uint4*)&Alds[ar][ac + 8] = *(const uint4*)(p + 8);
    }
    // stage B (thread t = output col n, 64 k of bf16 = 128 B)
    {
      const uint4* s4 = (const uint4*)(wrow + k0);
#pragma unroll
      for (int j = 0; j < 8; ++j) *(uint4*)&Blds[tid][j * 8] = s4[j];
    }
    __syncthreads();

    int lr = l & 15, lg = l >> 4;
#pragma unroll
    for (int kk = 0; kk < 2; ++kk) {
      bf16x8 a[4], b[4];
#pragma unroll
      for (int m = 0; m < 4; ++m)
        a[m] = *(const bf16x8*)&Alds[m * 16 + lr][kk * 32 + lg * 8];
#pragma unroll
      for (int n = 0; n < 4; ++n)
        b[n] = *(const bf16x8*)&Blds[w * 64 + n * 16 + lr][kk * 32 + lg * 8];
#pragma unroll
      for (int m = 0; m < 4; ++m)
#pragma unroll
        for (int n = 0; n < 4; ++n)
          acc[m][n] = __builtin_amdgcn_mfma_f32_16x16x32_bf16(a[m], b[n], acc[m][n], 0, 0, 0);
    }
    __syncthreads();
  }

  // epilogue: D[row=m*16+lg*4+r][col=w*64+n*16+lr]
  int lr = l & 15, lg = l >> 4;
#pragma unroll
  for (int m = 0; m < 4; ++m)
#pragma unroll
    for (int n = 0; n < 4; ++n)
#pragma unroll
      for (int r = 0; r < 4; ++r) {
        float v = acc[m][n][r] * scale;
        Hout[(size_t)(rowbase + m * 16 + lg * 4 + r) * HIDDEN + w * 64 + n * 16 + lr] =
            f2bf(silu_n(v));
      }
}

// ---- layer 4 + segment reduction ---------------------------------------
__global__ void k_l4(const unsigned short* __restrict__ H3, const unsigned short* __restrict__ W4t,
                     const int* __restrict__ perm, const int* __restrict__ species,
                     const int* __restrict__ sidx, const float* __restrict__ coeff,
                     float* __restrict__ out) {
  int w = threadIdx.x >> 6, l = threadIdx.x & 63;
  int row = blockIdx.x * 4 + w;
  int src = perm[row];
  if (src < 0) return;
  int sp = species[src];
  us4 h = *(const us4*)&H3[(size_t)row * HIDDEN + l * 4];
  us4 wv = *(const us4*)&W4t[sp * HIDDEN + l * 4];
  float sum = 0.f;
#pragma unroll
  for (int e = 0; e < 4; ++e) sum += bf2f(h[e]) * bf2f(wv[e]);
#pragma unroll
  for (int d = 32; d >= 1; d >>= 1) sum += __shfl_xor(sum, d, 64);
  if (l == 0)
    atomicAdd(&out[sidx[src]], sum * (0.0625f * 0.125f) + coeff[sp]);
}

// ---- launcher -----------------------------------------------------------
extern "C" void kernel_launch(void* const* d_in, const int* in_sizes, int n_in,
                              void* d_out, int out_size, void* d_ws, size_t ws_size,
                              hipStream_t stream) {
  const float* features = (const float*)d_in[0];
  const float* W1 = (const float*)d_in[1];
  const float* W2 = (const float*)d_in[2];
  const float* W3 = (const float*)d_in[3];
  const float* W4 = (const float*)d_in[4];
  const float* coeff = (const float*)d_in[5];
  const int* species = (const int*)d_in[6];
  const int* sidx = (const int*)d_in[7];
  float* out = (float*)d_out;

  char* ws = (char*)d_ws;
  int* ints = (int*)(ws + WS_INTS);
  int* perm = (int*)(ws + WS_PERM);
  unsigned short* W1t = (unsigned short*)(ws + WS_W1T);
  unsigned short* W2t = (unsigned short*)(ws + WS_W2T);
  unsigned short* W3t = (unsigned short*)(ws + WS_W3T);
  unsigned short* W4t = (unsigned short*)(ws + WS_W4T);
  unsigned short* H1 = (unsigned short*)(ws + WS_H1);
  unsigned short* H2 = (unsigned short*)(ws + WS_H2);

  // species bucketing
  k_init<<<(MPAD + 255) / 256, 256, 0, stream>>>(ints, perm, out);
  k_count<<<NATOMS / 256, 256, 0, stream>>>(species, ints);
  k_offsets<<<1, 1, 0, stream>>>(ints);
  k_scatter<<<NATOMS / 256, 256, 0, stream>>>(species, ints, perm);

  // weight prep: bf16, [sp][N][K] transposed
  k_transpose<<<NSPEC * (NFEAT / 64) * (HIDDEN / 64), 256, 0, stream>>>(W1, W1t, NFEAT, HIDDEN);
  k_transpose<<<NSPEC * (HIDDEN / 64) * (HIDDEN / 64), 256, 0, stream>>>(W2, W2t, HIDDEN, HIDDEN);
  k_transpose<<<NSPEC * (HIDDEN / 64) * (HIDDEN / 64), 256, 0, stream>>>(W3, W3t, HIDDEN, HIDDEN);
  k_w4<<<NSPEC, 256, 0, stream>>>(W4, W4t);

  // MLP layers
  const float s1 = 1.f / sqrtf((float)NFEAT);
  const float s2 = 1.f / 16.f;
  k_mlp<NFEAT, true><<<MTILES, 256, 0, stream>>>(features, nullptr, W1t, H1, perm, ints + 8, s1);
  k_mlp<HIDDEN, false><<<MTILES, 256, 0, stream>>>(nullptr, H1, W2t, H2, perm, ints + 8, s2);
  k_mlp<HIDDEN, false><<<MTILES, 256, 0, stream>>>(nullptr, H2, W3t, H1, perm, ints + 8, s2);

  // layer 4 + segment sum + composition term
  k_l4<<<MPAD / 4, 256, 0, stream>>>(H1, W4t, perm, species, sidx, coeff, out);
}